// Round 11
// baseline (774.223 us; speedup 1.0000x reference)
//
#include <hip/hip_runtime.h>
#include <hip/hip_bf16.h>

typedef __attribute__((ext_vector_type(8))) short short8;
typedef __attribute__((ext_vector_type(4))) short short4_t;
typedef __attribute__((ext_vector_type(4))) float floatx4;

#define MFMA_B16(a,b,c) __builtin_amdgcn_mfma_f32_16x16x32_bf16((a),(b),(c),0,0,0)

__device__ __forceinline__ short f2bf(float f) {
    union { __hip_bfloat16 h; short s; } u;
    u.h = __float2bfloat16(f);
    return u.s;
}

union S8U { short4_t h[2]; short8 v; };

// ---------------- problem constants ----------------
#define N_FRAMES 4096
#define C_IN     9
#define POS      121
#define NF       64
#define FC_K     7744     // k = p*64 + c
#define ISTR     20       // conv0 input LDS stride (elems)
#define FSZ      10816    // 169*64 elems per frame LDS image

// ---------------- workspace offsets (bytes) ----------------
#define OFF_W0    0                       // [9][64][16] bf16 (18432 B)
#define OFF_WP    18432                   // [7][9][64][64] bf16 (516096 B)
#define OFF_FCP   534528                  // [64][7744] bf16, k=p*64+c (991232 B)
#define OFF_WIHT  1525760                 // [64][256] f32 (65536 B)
#define OFF_BSUM  1591296                 // [256] f32 (1024 B)
#define OFF_ACTS  1592320                 // [4096][7744] bf16 (63438848 B)
#define OFF_XG    66079744                // [4096][256] f32 (4194304 B)
#define OFF_HOUT  70274048                // [4096][64] f32 (1048576 B)  end=71322624

// ================= prep: pack conv weights, w_ih^T, biases =================
__global__ __launch_bounds__(256) void prep_kernel(
    const float* __restrict__ conv0_w, const float* __restrict__ conv_ws,
    const float* __restrict__ w_ih,
    const float* __restrict__ b_ih, const float* __restrict__ b_hh,
    short* __restrict__ w0, short* __restrict__ wpk,
    float* __restrict__ wihT, float* __restrict__ bsum)
{
    int idx = blockIdx.x*256 + threadIdx.x;
    if (idx < 9216) {  // conv0: [o9][o][ci16]
        int o9 = idx >> 10; int r = idx & 1023; int o = r >> 4; int ci = r & 15;
        float v = (ci < 9) ? conv0_w[(o*9 + ci)*9 + o9] : 0.f;
        w0[idx] = f2bf(v);
        return;
    }
    idx -= 9216;
    if (idx < 258048) {  // conv1-7: [l][o9][o][ci]
        int l = idx / 36864; int r = idx % 36864; int o9 = r >> 12; int rr = r & 4095;
        int o = rr >> 6; int ci = rr & 63;
        wpk[idx] = f2bf(conv_ws[((l*64 + o)*64 + ci)*9 + o9]);
        return;
    }
    idx -= 258048;
    if (idx < 16384) {  // w_ih^T: [k][g]
        int k = idx >> 8; int g = idx & 255;
        wihT[idx] = w_ih[g*64 + k];
        return;
    }
    idx -= 16384;
    if (idx < 256) bsum[idx] = b_ih[idx] + b_hh[idx];
}

// ================= fc weight transpose: [u][c*121+p] f32 -> [u][p*64+c] bf16 =====
__global__ __launch_bounds__(256) void fc_transpose(
    const float* __restrict__ fc_w, short* __restrict__ fcp)
{
    __shared__ float row[FC_K];          // 30976 B
    const int u = blockIdx.x;
    const int tid = threadIdx.x;
    const float* src = fc_w + (size_t)u*FC_K;
    for (int i = tid; i < FC_K; i += 256) row[i] = src[i];
    __syncthreads();
    short* dst = fcp + (size_t)u*FC_K;
    for (int k2 = tid; k2 < FC_K; k2 += 256) {
        int p = k2 >> 6, c = k2 & 63;
        dst[k2] = f2bf(row[c*121 + p]);
    }
}

// ========== fused 8-layer conv stack: 4 waves / 2 frames per block ==========
// Swizzled act layout (per frame): cell (Y,X) of 13x13 grid, 64 ch in 8 groups
// of 8 bf16 (16B); group G at slot ((G + 11*Y + X + 4) & 7).
//   interior cell of logical p: slot = (G + p) & 7
//   tap cell (base + dy,dx):    slot = (G + p + 11*dy + dx + 4) & 7
// p = 16*j + m => p mod 8 = m mod 8: tap slot is uniform across j-tiles.
// N-split: wave (fr,nh) = frame fr, position tiles [4nh,4nh+4), all 64 out-ch,
// acc[4][4] = 64 AGPRs. R11: one-chunk A-PREFETCH software pipeline — R10's
// regression was exposed global A-load latency (4 loads/chunk, unroll-1, no
// cross-chunk motion). a_cur used in chunk c was loaded during chunk c-1, so
// its vmcnt wait lands ~150+ cyc after issue. +16 VGPR: total stays under the
// 192-reg quantization step (m69: waves/SIMD = floor(512/ceil64(regs))) -> 2
// waves/SIMD preserved. LDS 43264 B -> B-read volume stays at the halved
// (R10) level: ~84us/CU, below the 140us/CU MFMA floor.
__global__ __launch_bounds__(256) void conv_stack(
    const float* __restrict__ x,
    const float* __restrict__ conv0_b,
    const float* __restrict__ conv_bs,
    const short* __restrict__ w0,
    const short* __restrict__ wpk,
    short* __restrict__ acts_out)
{
    __shared__ alignas(16) short act[2*FSZ];   // 43264 B
    const int tid  = threadIdx.x;
    const int lane = tid & 63;
    const int w    = tid >> 6;     // 0..3
    const int fr   = w >> 1;       // frame within block
    const int nh   = w & 1;        // N half: position tiles [4nh, 4nh+4)
    const int m    = lane & 15;
    const int kg   = lane >> 4;
    const int ht   = tid & 127;    // half-block thread (staging helpers)
    const int hf   = tid >> 7;     // half-block frame

    short* actf = act + fr*FSZ;    // this wave's frame image
    char*  actb = (char*)actf;

    const short8 zero8 = {0,0,0,0,0,0,0,0};
    const floatx4 fzero = {0.f,0.f,0.f,0.f};

    // zero conv0 staging region of each frame (3380 elems stride-20, pad 3392)
    {
        short* ab = act + hf*FSZ;
        for (int i = ht*8; i < 3392; i += 1024) *(short8*)(&ab[i]) = zero8;
    }
    __syncthreads();

    // stage input frames fp32 -> bf16 ([Y][X][ci] stride 20; x is [ci][y][x])
    {
        short* ab = act + hf*FSZ;
        const float* xf = x + (size_t)(blockIdx.x*2 + hf)*(C_IN*POS);
        for (int i = ht; i < C_IN*POS; i += 128) {
            int ci = i / POS;
            int p  = i - ci*POS;
            int yy = p / 11;
            int xx = p - yy*11;
            ab[((yy+1)*13 + (xx+1))*ISTR + ci] = f2bf(xf[i]);
        }
    }
    __syncthreads();

    floatx4 acc[4][4];
    #pragma unroll
    for (int mt=0;mt<4;mt++)
        #pragma unroll
        for (int jj=0;jj<4;jj++) acc[mt][jj] = fzero;

    // per-jj tap-base cell (clamped); vbase = byte base in swizzled layout
    int cellA[4], vbase[4];
    #pragma unroll
    for (int jj = 0; jj < 4; ++jj) {
        int p = (nh*4 + jj)*16 + m;
        int pc = (p <= 120) ? p : 120;
        int yy = pc / 11, xx = pc - yy*11;
        cellA[jj] = yy*13 + xx;
        vbase[jj] = cellA[jj]*128;
    }

    // ---- conv0 (K real 16, padded to 32; kg>=2 contributes zeros via a) ----
    {
        const bool kz  = (kg >= 2);
        const int  kgl = (kg & 1)*8;
        const short* w0w = w0 + m*16 + kgl;
        #pragma unroll 1
        for (int dy = 0; dy < 3; ++dy) {
            #pragma unroll 1
            for (int dx = 0; dx < 3; ++dx) {
                const short* w9 = w0w + (dy*3+dx)*1024;
                const int so = (dy*13+dx)*ISTR + kgl;
                short8 a[4];
                #pragma unroll
                for (int mt=0;mt<4;mt++) {
                    short8 t = *(const short8*)(w9 + mt*256);   // 16 ch * 16
                    a[mt] = kz ? zero8 : t;
                }
                #pragma unroll
                for (int jj=0;jj<4;jj++) {
                    const short* bp = actf + cellA[jj]*ISTR + so;
                    S8U t;
                    t.h[0] = *(const short4_t*)(bp);
                    t.h[1] = *(const short4_t*)(bp + 4);
                    short8 b = t.v;
                    #pragma unroll
                    for (int mt=0;mt<4;mt++)
                        acc[mt][jj] = MFMA_B16(a[mt], b, acc[mt][jj]);
                }
            }
        }
    }

    // conv0 input dead; zero the full swizzled act buffers
    __syncthreads();
    {
        short* ab = act + hf*FSZ;
        for (int i = ht*8; i < FSZ; i += 1024) *(short8*)(&ab[i]) = zero8;
    }
    __syncthreads();

    // epilogue: bias+relu+bf16 -> swizzled act interior (wave writes its 4 tiles)
    auto epilogue = [&](const float* bias) {
        __syncthreads();
        #pragma unroll
        for (int mt=0;mt<4;mt++) {
            const int ch0 = mt*16 + kg*4;
            const int gw  = ch0 >> 3;
            const int off = 1792 + (((gw + m) & 7)<<4) + (kg&1)*8; // slot uniform in j
            floatx4 bb = *(const floatx4*)(bias + ch0);
            #pragma unroll
            for (int jj=0;jj<4;jj++) {
                floatx4 v = acc[mt][jj];
                acc[mt][jj] = fzero;
                int p = (nh*4 + jj)*16 + m;
                if (p > 120) continue;
                short4_t sv;
                sv.x = f2bf(fmaxf(v.x + bb.x, 0.f));
                sv.y = f2bf(fmaxf(v.y + bb.y, 0.f));
                sv.z = f2bf(fmaxf(v.z + bb.z, 0.f));
                sv.w = f2bf(fmaxf(v.w + bb.w, 0.f));
                *(short4_t*)(actb + vbase[jj] + off) = sv;
            }
        }
        __syncthreads();
    };

    epilogue(conv0_b);

    // ---- conv layers 1..7: linearized 18-chunk loop with 1-chunk A prefetch ----
    for (int l = 1; l < 8; ++l) {
        const short* wl = wpk + (l-1)*36864 + m*64 + kg*8;
        short8 a_cur[4];
        #pragma unroll
        for (int mt=0;mt<4;mt++) a_cur[mt] = *(const short8*)(wl + mt*1024); // chunk 0: tap(0,0) kc0
        #pragma unroll 1
        for (int c = 0; c < 18; ++c) {
            const int t  = c >> 1, kc = c & 1;
            const int dy = (t*11) >> 5, dx = t - dy*3;       // t/3, t%3 (t<9)
            const int soff = (dy*13+dx)*128
                           + (((m + kg + dy*11 + dx + 4 + kc*4) & 7) << 4);
            // prefetch next chunk's A-frags (global; vmcnt waits land next iter)
            const int cn  = (c < 17) ? c+1 : c;
            const int tn  = cn >> 1, kcn = cn & 1;
            const int dyn = (tn*11) >> 5, dxn = tn - dyn*3;
            const short* wn = wl + (dyn*3+dxn)*4096 + kcn*32;
            short8 a_nxt[4];
            #pragma unroll
            for (int mt=0;mt<4;mt++) a_nxt[mt] = *(const short8*)(wn + mt*1024);
            // current chunk: 4 B LDS reads + 16 MFMAs
            #pragma unroll
            for (int jj=0;jj<4;jj++) {
                short8 b = *(const short8*)(actb + vbase[jj] + soff);
                #pragma unroll
                for (int mt=0;mt<4;mt++)
                    acc[mt][jj] = MFMA_B16(a_cur[mt], b, acc[mt][jj]);
            }
            #pragma unroll
            for (int mt=0;mt<4;mt++) a_cur[mt] = a_nxt[mt];
        }
        epilogue(conv_bs + (l-1)*NF);
    }

    // final copy: acts[f][p*64 + c], un-swizzled, coalesced 16B global writes
    {
        const char* ab = (const char*)(act + hf*FSZ);
        short* dst = acts_out + (size_t)(blockIdx.x*2 + hf)*FC_K;
        for (int it = 0; it < 8; ++it) {
            int q = ht + it*128;
            if (q < 968) {                    // 121 pos * 8 ch-groups
                int p = q >> 3, G = q & 7;
                int yy = p / 11, xx = p - yy*11;
                int cell = (yy+1)*13 + (xx+1);
                int slot = (G + p) & 7;
                short8 v = *(const short8*)(ab + cell*128 + slot*16);
                *(short8*)(dst + q*8) = v;
            }
        }
    }
}

// ===== fused FC + xg: xg[f][g] = relu(acts[f]@fcp^T + fc_b) @ wihT + bsum =====
__global__ __launch_bounds__(256) void fc_xg_kernel(
    const short* __restrict__ acts, const short* __restrict__ fcp,
    const float* __restrict__ fc_b, const float* __restrict__ wihT,
    const float* __restrict__ bsum, float* __restrict__ xg)
{
    __shared__ alignas(16) float red[3*64*16];   // 12288 B
    __shared__ alignas(16) float fbuf[16*64];    // 4096 B
    const int tid  = threadIdx.x;
    const int lane = tid & 63;
    const int w    = tid >> 6;
    const int m    = lane & 15;
    const int kg   = lane >> 4;
    const int bm   = blockIdx.x;     // 256 blocks x 16 frames

    const floatx4 fzero = {0.f,0.f,0.f,0.f};
    floatx4 acc[4];
    #pragma unroll
    for (int nt=0;nt<4;nt++) acc[nt] = fzero;

    const short* arow = acts + (size_t)(bm*16 + m)*FC_K + kg*8;
    const short* brow = fcp + (size_t)m*FC_K + kg*8;

    for (int kc = w; kc < 242; kc += 4) {   // K split across 4 waves
        short8 a = *(const short8*)(arow + kc*32);
        #pragma unroll
        for (int nt=0;nt<4;nt++) {
            short8 b = *(const short8*)(brow + (size_t)nt*16*FC_K + kc*32);
            acc[nt] = MFMA_B16(a, b, acc[nt]);
        }
    }

    if (w > 0) {
        #pragma unroll
        for (int nt=0;nt<4;nt++)
            *(floatx4*)(&red[((w-1)*64 + lane)*16 + nt*4]) = acc[nt];
    }
    __syncthreads();
    if (w == 0) {
        #pragma unroll
        for (int nt=0;nt<4;nt++)
            for (int j=0;j<3;j++)
                acc[nt] += *(const floatx4*)(&red[(j*64 + lane)*16 + nt*4]);
        #pragma unroll
        for (int nt=0;nt<4;nt++) {
            int unit = nt*16 + m;
            float bias = fc_b[unit];
            int fr = kg*4;                    // local frame 0..15
            fbuf[(fr+0)*NF + unit] = fmaxf(acc[nt].x + bias, 0.f);
            fbuf[(fr+1)*NF + unit] = fmaxf(acc[nt].y + bias, 0.f);
            fbuf[(fr+2)*NF + unit] = fmaxf(acc[nt].z + bias, 0.f);
            fbuf[(fr+3)*NF + unit] = fmaxf(acc[nt].w + bias, 0.f);
        }
    }
    __syncthreads();

    // xg phase: thread g computes 16 frames x 1 gate
    {
        const int g = tid;
        float a[16];
        float bs = bsum[g];
        #pragma unroll
        for (int i=0;i<16;i++) a[i] = bs;
        for (int k=0;k<64;k++) {
            float wk = wihT[k*256 + g];
            #pragma unroll
            for (int i=0;i<16;i++) a[i] += fbuf[i*64 + k] * wk;
        }
        float* xo = xg + (size_t)(bm*16)*256 + g;
        #pragma unroll
        for (int i=0;i<16;i++) xo[i*256] = a[i];
    }
}

// ================= LSTM recurrence =================
// fast sigmoid/tanh: __expf + hw rcp; saturate correctly at +/-inf
__device__ __forceinline__ float sigmf_(float v){
    return __builtin_amdgcn_rcpf(1.f + __expf(-v));
}
__device__ __forceinline__ float tanhf_(float v){
    return 1.f - 2.f*__builtin_amdgcn_rcpf(__expf(2.f*v) + 1.f);
}

__global__ __launch_bounds__(128) void lstm_kernel(
    const float* __restrict__ xg, const float* __restrict__ whh,
    float* __restrict__ hout)
{
    __shared__ alignas(16) float hbuf[64];
    __shared__ alignas(16) float gbuf[256];
    const int t = threadIdx.x;
    const int b = blockIdx.x;

    float4 w0v[16], w1v[16];
    #pragma unroll
    for (int k=0;k<16;k++) w0v[k] = *(const float4*)(whh + t*64 + k*4);
    #pragma unroll
    for (int k=0;k<16;k++) w1v[k] = *(const float4*)(whh + (t+128)*64 + k*4);

    float c = 0.f;
    if (t < 64) hbuf[t] = 0.f;
    __syncthreads();

    const float* xr = xg + (size_t)(b*128)*256;
    float nA = xr[t];
    float nB = xr[t+128];

    for (int ts=0; ts<128; ++ts) {
        float aA = nA, aB = nB;
        if (ts + 1 < 128) {
            const float* xn = xr + (ts+1)*256;
            nA = xn[t];
            nB = xn[t+128];
        }
        #pragma unroll
        for (int k=0;k<16;k++) {
            float4 hv = *(const float4*)(&hbuf[k*4]);
            aA += hv.x*w0v[k].x + hv.y*w0v[k].y + hv.z*w0v[k].z + hv.w*w0v[k].w;
            aB += hv.x*w1v[k].x + hv.y*w1v[k].y + hv.z*w1v[k].z + hv.w*w1v[k].w;
        }
        gbuf[t] = aA;
        gbuf[t+128] = aB;
        __syncthreads();
        if (t < 64) {   // gate order i,f,g,o
            float ig = sigmf_(gbuf[t]);
            float fg = sigmf_(gbuf[64+t]);
            float gg = tanhf_(gbuf[128+t]);
            float og = sigmf_(gbuf[192+t]);
            c = fg*c + ig*gg;
            float h = og*tanhf_(c);
            hbuf[t] = h;
            hout[(b*128+ts)*64 + t] = h;
        }
        __syncthreads();
    }
}

// ================= policy/value heads (fp32) =================
__global__ __launch_bounds__(64) void heads_kernel(
    const float* __restrict__ hout,
    const float* __restrict__ p1w, const float* __restrict__ p1b,
    const float* __restrict__ p2w, const float* __restrict__ p2b,
    const float* __restrict__ v1w, const float* __restrict__ v1b,
    const float* __restrict__ v2w, const float* __restrict__ v2b,
    float* __restrict__ out)
{
    __shared__ alignas(16) float hbuf[64];
    __shared__ alignas(16) float a1[128];
    __shared__ alignas(16) float a2[128];
    const int lane = threadIdx.x;
    for (int fi=0; fi<4; ++fi) {
        const int f = blockIdx.x*4 + fi;
        hbuf[lane] = hout[f*64 + lane];
        __syncthreads();
        #pragma unroll
        for (int uu=0; uu<2; ++uu) {
            const int u = lane + uu*64;
            float s1 = p1b[u], s2 = v1b[u];
            const float4* wp1 = (const float4*)(p1w + u*64);
            const float4* wv1 = (const float4*)(v1w + u*64);
            #pragma unroll
            for (int k=0;k<16;k++) {
                float4 h4 = *(const float4*)(&hbuf[k*4]);
                float4 w4 = wp1[k];
                s1 += h4.x*w4.x + h4.y*w4.y + h4.z*w4.z + h4.w*w4.w;
                float4 q4 = wv1[k];
                s2 += h4.x*q4.x + h4.y*q4.y + h4.z*q4.z + h4.w*q4.w;
            }
            a1[u] = fmaxf(s1, 0.f);
            a2[u] = fmaxf(s2, 0.f);
        }
        __syncthreads();
        if (lane < 6) {
            float s = p2b[lane];
            const float* wr = p2w + lane*128;
            #pragma unroll
            for (int j=0;j<128;j++) s += a1[j]*wr[j];
            out[f*6 + lane] = s;
        }
        if (lane == 6) {
            float s = v2b[0];
            #pragma unroll
            for (int j=0;j<128;j++) s += a2[j]*v2w[j];
            out[24576 + f] = s;
        }
        __syncthreads();
    }
}

extern "C" void kernel_launch(void* const* d_in, const int* in_sizes, int n_in,
                              void* d_out, int out_size, void* d_ws, size_t ws_size,
                              hipStream_t stream) {
    const float* x       = (const float*)d_in[0];
    const float* conv0_w = (const float*)d_in[1];
    const float* conv0_b = (const float*)d_in[2];
    const float* conv_ws = (const float*)d_in[3];
    const float* conv_bs = (const float*)d_in[4];
    const float* fc_w    = (const float*)d_in[5];
    const float* fc_b    = (const float*)d_in[6];
    const float* w_ih    = (const float*)d_in[7];
    const float* w_hh    = (const float*)d_in[8];
    const float* b_ih    = (const float*)d_in[9];
    const float* b_hh    = (const float*)d_in[10];
    const float* p1_w    = (const float*)d_in[11];
    const float* p1_b    = (const float*)d_in[12];
    const float* p2_w    = (const float*)d_in[13];
    const float* p2_b    = (const float*)d_in[14];
    const float* v1_w    = (const float*)d_in[15];
    const float* v1_b    = (const float*)d_in[16];
    const float* v2_w    = (const float*)d_in[17];
    const float* v2_b    = (const float*)d_in[18];
    float* out = (float*)d_out;

    char* ws = (char*)d_ws;
    short* w0    = (short*)(ws + OFF_W0);
    short* wpk   = (short*)(ws + OFF_WP);
    short* fcp   = (short*)(ws + OFF_FCP);
    float* wihT  = (float*)(ws + OFF_WIHT);
    float* bsum  = (float*)(ws + OFF_BSUM);
    short* acts  = (short*)(ws + OFF_ACTS);
    float* xgb   = (float*)(ws + OFF_XG);
    float* hout  = (float*)(ws + OFF_HOUT);

    prep_kernel<<<1109, 256, 0, stream>>>(conv0_w, conv_ws, w_ih, b_ih, b_hh,
                                          w0, wpk, wihT, bsum);
    fc_transpose<<<64, 256, 0, stream>>>(fc_w, fcp);
    conv_stack<<<N_FRAMES/2, 256, 0, stream>>>(x, conv0_b, conv_bs, w0, wpk, acts);
    fc_xg_kernel<<<256, 256, 0, stream>>>(acts, fcp, fc_b, wihT, bsum, xgb);
    lstm_kernel<<<32, 128, 0, stream>>>(xgb, w_hh, hout);
    heads_kernel<<<1024, 64, 0, stream>>>(hout, p1_w, p1_b, p2_w, p2_b,
                                          v1_w, v1_b, v2_w, v2_b, out);
}

// Round 12
// 562.255 us; speedup vs baseline: 1.3770x; 1.3770x over previous
//
#include <hip/hip_runtime.h>
#include <hip/hip_bf16.h>

typedef __attribute__((ext_vector_type(8))) short short8;
typedef __attribute__((ext_vector_type(4))) short short4_t;
typedef __attribute__((ext_vector_type(4))) float floatx4;

#define MFMA_B16(a,b,c) __builtin_amdgcn_mfma_f32_16x16x32_bf16((a),(b),(c),0,0,0)

__device__ __forceinline__ short f2bf(float f) {
    union { __hip_bfloat16 h; short s; } u;
    u.h = __float2bfloat16(f);
    return u.s;
}

union S8U { short4_t h[2]; short8 v; };

// ---------------- problem constants ----------------
#define N_FRAMES 4096
#define C_IN     9
#define POS      121
#define NF       64
#define FC_K     7744     // k = p*64 + c
#define ISTR     20       // conv0 input LDS stride (elems)
#define FSZ      10816    // 169*64 elems per frame LDS image

// ---------------- workspace offsets (bytes) ----------------
#define OFF_W0    0                       // [9][64][16] bf16 (18432 B)
#define OFF_WP    18432                   // [7][9][64][64] bf16 (516096 B)
#define OFF_FCP   534528                  // [64][7744] bf16, k=p*64+c (991232 B)
#define OFF_WIHT  1525760                 // [64][256] f32 (65536 B)
#define OFF_BSUM  1591296                 // [256] f32 (1024 B)
#define OFF_ACTS  1592320                 // [4096][7744] bf16 (63438848 B)
#define OFF_XG    66079744                // [4096][256] f32 (4194304 B)
#define OFF_HOUT  70274048                // [4096][64] f32 (1048576 B)  end=71322624

// ================= prep: pack conv weights, w_ih^T, biases =================
__global__ __launch_bounds__(256) void prep_kernel(
    const float* __restrict__ conv0_w, const float* __restrict__ conv_ws,
    const float* __restrict__ w_ih,
    const float* __restrict__ b_ih, const float* __restrict__ b_hh,
    short* __restrict__ w0, short* __restrict__ wpk,
    float* __restrict__ wihT, float* __restrict__ bsum)
{
    int idx = blockIdx.x*256 + threadIdx.x;
    if (idx < 9216) {  // conv0: [o9][o][ci16]
        int o9 = idx >> 10; int r = idx & 1023; int o = r >> 4; int ci = r & 15;
        float v = (ci < 9) ? conv0_w[(o*9 + ci)*9 + o9] : 0.f;
        w0[idx] = f2bf(v);
        return;
    }
    idx -= 9216;
    if (idx < 258048) {  // conv1-7: [l][o9][o][ci]
        int l = idx / 36864; int r = idx % 36864; int o9 = r >> 12; int rr = r & 4095;
        int o = rr >> 6; int ci = rr & 63;
        wpk[idx] = f2bf(conv_ws[((l*64 + o)*64 + ci)*9 + o9]);
        return;
    }
    idx -= 258048;
    if (idx < 16384) {  // w_ih^T: [k][g]
        int k = idx >> 8; int g = idx & 255;
        wihT[idx] = w_ih[g*64 + k];
        return;
    }
    idx -= 16384;
    if (idx < 256) bsum[idx] = b_ih[idx] + b_hh[idx];
}

// ================= fc weight transpose: [u][c*121+p] f32 -> [u][p*64+c] bf16 =====
__global__ __launch_bounds__(256) void fc_transpose(
    const float* __restrict__ fc_w, short* __restrict__ fcp)
{
    __shared__ float row[FC_K];          // 30976 B
    const int u = blockIdx.x;
    const int tid = threadIdx.x;
    const float* src = fc_w + (size_t)u*FC_K;
    for (int i = tid; i < FC_K; i += 256) row[i] = src[i];
    __syncthreads();
    short* dst = fcp + (size_t)u*FC_K;
    for (int k2 = tid; k2 < FC_K; k2 += 256) {
        int p = k2 >> 6, c = k2 & 63;
        dst[k2] = f2bf(row[c*121 + p]);
    }
}

// ========== fused 8-layer conv stack: 4 waves / 2 frames per block ==========
// REVERTED to R9's proven M-split structure (344us) after the N-split line
// (R10/R11) regressed twice: per-wave 2 A-loads : 8 B-reads : 16 MFMA is the
// best-measured instruction mix at the hard 2-waves/SIMD register ceiling.
// Single delta vs R9: kc loop fully unrolled -> per tap one straight-line
// burst of 4 global A-loads + 16 ds_reads feeding 32 MFMAs (2x in-flight
// memory ops per wait point). VGPR 88 -> ~104; +64 AGPR = 168 -> same
// ceil64=192 quantization bin as R9 -> occupancy unchanged.
// Swizzled act layout (per frame): cell (Y,X) of 13x13 grid, 64 ch in 8
// groups of 8 bf16; group G at slot ((G + 11*Y + X + 4) & 7).
//   interior cell of logical p: slot = (G + p) & 7
//   tap cell (base + dy,dx):    slot = (G + p + 11*dy + dx + 4) & 7
// p = 16j + m => slot is uniform across the 8 j-tiles.
__global__ __launch_bounds__(256) void conv_stack(
    const float* __restrict__ x,
    const float* __restrict__ conv0_b,
    const float* __restrict__ conv_bs,
    const short* __restrict__ w0,
    const short* __restrict__ wpk,
    short* __restrict__ acts_out)
{
    __shared__ alignas(16) short act[2*FSZ];   // 43264 B
    const int tid  = threadIdx.x;
    const int lane = tid & 63;
    const int w    = tid >> 6;     // 0..3
    const int fr   = w >> 1;       // frame within block
    const int mh   = w & 1;        // M half: out-channels [32*mh, 32*mh+32)
    const int m    = lane & 15;
    const int kg   = lane >> 4;
    const int ht   = tid & 127;    // half-block thread (staging helpers)
    const int hf   = tid >> 7;     // half-block frame

    short* actf = act + fr*FSZ;    // this wave's frame image
    char*  actb = (char*)actf;

    const short8 zero8 = {0,0,0,0,0,0,0,0};
    const floatx4 fzero = {0.f,0.f,0.f,0.f};

    // zero conv0 staging region of each frame (3380 elems stride-20, pad 3392)
    {
        short* ab = act + hf*FSZ;
        for (int i = ht*8; i < 3392; i += 1024) *(short8*)(&ab[i]) = zero8;
    }
    __syncthreads();

    // stage input frames fp32 -> bf16 ([Y][X][ci] stride 20; x is [ci][y][x])
    {
        short* ab = act + hf*FSZ;
        const float* xf = x + (size_t)(blockIdx.x*2 + hf)*(C_IN*POS);
        for (int i = ht; i < C_IN*POS; i += 128) {
            int ci = i / POS;
            int p  = i - ci*POS;
            int yy = p / 11;
            int xx = p - yy*11;
            ab[((yy+1)*13 + (xx+1))*ISTR + ci] = f2bf(xf[i]);
        }
    }
    __syncthreads();

    floatx4 acc[2][8];
    #pragma unroll
    for (int mt=0;mt<2;mt++)
        #pragma unroll
        for (int j=0;j<8;j++) acc[mt][j] = fzero;

    // per-j tap-base cell (clamped); vbase = byte base in swizzled layout
    int cellA[8], vbase[8];
    #pragma unroll
    for (int j = 0; j < 8; ++j) {
        int p = j*16 + m;
        int pc = (p <= 120) ? p : 120;
        int yy = pc / 11, xx = pc - yy*11;
        cellA[j] = yy*13 + xx;
        vbase[j] = cellA[j]*128;
    }

    // ---- conv0 (K real 16, padded to 32; kg>=2 contributes zeros via a) ----
    {
        const bool kz  = (kg >= 2);
        const int  kgl = (kg & 1)*8;
        const short* w0w = w0 + (mh*32 + m)*16 + kgl;
        #pragma unroll 1
        for (int dy = 0; dy < 3; ++dy) {
            #pragma unroll 1
            for (int dx = 0; dx < 3; ++dx) {
                const short* w9 = w0w + (dy*3+dx)*1024;
                const int so = (dy*13+dx)*ISTR + kgl;
                short8 a[2];
                #pragma unroll
                for (int mt=0;mt<2;mt++) {
                    short8 t = *(const short8*)(w9 + mt*256);   // 16 ch * 16
                    a[mt] = kz ? zero8 : t;
                }
                #pragma unroll
                for (int j=0;j<8;j++) {
                    const short* bp = actf + cellA[j]*ISTR + so;
                    S8U t;
                    t.h[0] = *(const short4_t*)(bp);
                    t.h[1] = *(const short4_t*)(bp + 4);
                    short8 b = t.v;
                    #pragma unroll
                    for (int mt=0;mt<2;mt++)
                        acc[mt][j] = MFMA_B16(a[mt], b, acc[mt][j]);
                }
            }
        }
    }

    // conv0 input dead; zero the full swizzled act buffers
    __syncthreads();
    {
        short* ab = act + hf*FSZ;
        for (int i = ht*8; i < FSZ; i += 1024) *(short8*)(&ab[i]) = zero8;
    }
    __syncthreads();

    // epilogue: bias+relu+bf16 -> swizzled act interior (wave writes its half)
    auto epilogue = [&](const float* bias) {
        __syncthreads();
        #pragma unroll
        for (int mt=0;mt<2;mt++) {
            const int ch0 = mh*32 + mt*16 + kg*4;
            const int gw  = ch0 >> 3;
            const int off = 1792 + (((gw + m) & 7)<<4) + (kg&1)*8; // slot uniform in j
            floatx4 bb = *(const floatx4*)(bias + ch0);
            #pragma unroll
            for (int j=0;j<8;j++) {
                floatx4 v = acc[mt][j];
                acc[mt][j] = fzero;
                int p = j*16 + m;
                if (p > 120) continue;
                short4_t sv;
                sv.x = f2bf(fmaxf(v.x + bb.x, 0.f));
                sv.y = f2bf(fmaxf(v.y + bb.y, 0.f));
                sv.z = f2bf(fmaxf(v.z + bb.z, 0.f));
                sv.w = f2bf(fmaxf(v.w + bb.w, 0.f));
                *(short4_t*)(actb + vbase[j] + off) = sv;
            }
        }
        __syncthreads();
    };

    epilogue(conv0_b);

    // ---- conv layers 1..7: unroll-1 taps, kc FULLY UNROLLED (R12 delta) ----
    for (int l = 1; l < 8; ++l) {
        const short* wl = wpk + (l-1)*36864 + (mh*32 + m)*64 + kg*8;
        #pragma unroll 1
        for (int dy = 0; dy < 3; ++dy) {
            #pragma unroll 1
            for (int dx = 0; dx < 3; ++dx) {
                const short* wo = wl + (dy*3+dx)*4096;
                const int sb = (dy*13+dx)*128;        // cell byte shift
                const int cu = dy*11 + dx + 4 + kg + m;
                #pragma unroll
                for (int kc = 0; kc < 2; ++kc) {
                    short8 a[2];
                    #pragma unroll
                    for (int mt=0;mt<2;mt++)
                        a[mt] = *(const short8*)(wo + mt*1024 + kc*32);
                    const int soff = sb + (((cu + kc*4) & 7)<<4); // slot uniform in j
                    #pragma unroll
                    for (int j=0;j<8;j++) {
                        short8 b = *(const short8*)(actb + vbase[j] + soff);
                        #pragma unroll
                        for (int mt=0;mt<2;mt++)
                            acc[mt][j] = MFMA_B16(a[mt], b, acc[mt][j]);
                    }
                }
            }
        }
        epilogue(conv_bs + (l-1)*NF);
    }

    // final copy: acts[f][p*64 + c], un-swizzled, coalesced 16B global writes
    {
        const char* ab = (const char*)(act + hf*FSZ);
        short* dst = acts_out + (size_t)(blockIdx.x*2 + hf)*FC_K;
        for (int it = 0; it < 8; ++it) {
            int q = ht + it*128;
            if (q < 968) {                    // 121 pos * 8 ch-groups
                int p = q >> 3, G = q & 7;
                int yy = p / 11, xx = p - yy*11;
                int cell = (yy+1)*13 + (xx+1);
                int slot = (G + p) & 7;
                short8 v = *(const short8*)(ab + cell*128 + slot*16);
                *(short8*)(dst + q*8) = v;
            }
        }
    }
}

// ===== fused FC + xg: xg[f][g] = relu(acts[f]@fcp^T + fc_b) @ wihT + bsum =====
__global__ __launch_bounds__(256) void fc_xg_kernel(
    const short* __restrict__ acts, const short* __restrict__ fcp,
    const float* __restrict__ fc_b, const float* __restrict__ wihT,
    const float* __restrict__ bsum, float* __restrict__ xg)
{
    __shared__ alignas(16) float red[3*64*16];   // 12288 B
    __shared__ alignas(16) float fbuf[16*64];    // 4096 B
    const int tid  = threadIdx.x;
    const int lane = tid & 63;
    const int w    = tid >> 6;
    const int m    = lane & 15;
    const int kg   = lane >> 4;
    const int bm   = blockIdx.x;     // 256 blocks x 16 frames

    const floatx4 fzero = {0.f,0.f,0.f,0.f};
    floatx4 acc[4];
    #pragma unroll
    for (int nt=0;nt<4;nt++) acc[nt] = fzero;

    const short* arow = acts + (size_t)(bm*16 + m)*FC_K + kg*8;
    const short* brow = fcp + (size_t)m*FC_K + kg*8;

    for (int kc = w; kc < 242; kc += 4) {   // K split across 4 waves
        short8 a = *(const short8*)(arow + kc*32);
        #pragma unroll
        for (int nt=0;nt<4;nt++) {
            short8 b = *(const short8*)(brow + (size_t)nt*16*FC_K + kc*32);
            acc[nt] = MFMA_B16(a, b, acc[nt]);
        }
    }

    if (w > 0) {
        #pragma unroll
        for (int nt=0;nt<4;nt++)
            *(floatx4*)(&red[((w-1)*64 + lane)*16 + nt*4]) = acc[nt];
    }
    __syncthreads();
    if (w == 0) {
        #pragma unroll
        for (int nt=0;nt<4;nt++)
            for (int j=0;j<3;j++)
                acc[nt] += *(const floatx4*)(&red[(j*64 + lane)*16 + nt*4]);
        #pragma unroll
        for (int nt=0;nt<4;nt++) {
            int unit = nt*16 + m;
            float bias = fc_b[unit];
            int fr = kg*4;                    // local frame 0..15
            fbuf[(fr+0)*NF + unit] = fmaxf(acc[nt].x + bias, 0.f);
            fbuf[(fr+1)*NF + unit] = fmaxf(acc[nt].y + bias, 0.f);
            fbuf[(fr+2)*NF + unit] = fmaxf(acc[nt].z + bias, 0.f);
            fbuf[(fr+3)*NF + unit] = fmaxf(acc[nt].w + bias, 0.f);
        }
    }
    __syncthreads();

    // xg phase: thread g computes 16 frames x 1 gate
    {
        const int g = tid;
        float a[16];
        float bs = bsum[g];
        #pragma unroll
        for (int i=0;i<16;i++) a[i] = bs;
        for (int k=0;k<64;k++) {
            float wk = wihT[k*256 + g];
            #pragma unroll
            for (int i=0;i<16;i++) a[i] += fbuf[i*64 + k] * wk;
        }
        float* xo = xg + (size_t)(bm*16)*256 + g;
        #pragma unroll
        for (int i=0;i<16;i++) xo[i*256] = a[i];
    }
}

// ================= LSTM recurrence =================
// fast sigmoid/tanh: __expf + hw rcp; saturate correctly at +/-inf
// (validated R10/R11: absmax unchanged at 2.441e-4)
__device__ __forceinline__ float sigmf_(float v){
    return __builtin_amdgcn_rcpf(1.f + __expf(-v));
}
__device__ __forceinline__ float tanhf_(float v){
    return 1.f - 2.f*__builtin_amdgcn_rcpf(__expf(2.f*v) + 1.f);
}

__global__ __launch_bounds__(128) void lstm_kernel(
    const float* __restrict__ xg, const float* __restrict__ whh,
    float* __restrict__ hout)
{
    __shared__ alignas(16) float hbuf[64];
    __shared__ alignas(16) float gbuf[256];
    const int t = threadIdx.x;
    const int b = blockIdx.x;

    float4 w0v[16], w1v[16];
    #pragma unroll
    for (int k=0;k<16;k++) w0v[k] = *(const float4*)(whh + t*64 + k*4);
    #pragma unroll
    for (int k=0;k<16;k++) w1v[k] = *(const float4*)(whh + (t+128)*64 + k*4);

    float c = 0.f;
    if (t < 64) hbuf[t] = 0.f;
    __syncthreads();

    const float* xr = xg + (size_t)(b*128)*256;
    float nA = xr[t];
    float nB = xr[t+128];

    for (int ts=0; ts<128; ++ts) {
        float aA = nA, aB = nB;
        if (ts + 1 < 128) {
            const float* xn = xr + (ts+1)*256;
            nA = xn[t];
            nB = xn[t+128];
        }
        #pragma unroll
        for (int k=0;k<16;k++) {
            float4 hv = *(const float4*)(&hbuf[k*4]);
            aA += hv.x*w0v[k].x + hv.y*w0v[k].y + hv.z*w0v[k].z + hv.w*w0v[k].w;
            aB += hv.x*w1v[k].x + hv.y*w1v[k].y + hv.z*w1v[k].z + hv.w*w1v[k].w;
        }
        gbuf[t] = aA;
        gbuf[t+128] = aB;
        __syncthreads();
        if (t < 64) {   // gate order i,f,g,o
            float ig = sigmf_(gbuf[t]);
            float fg = sigmf_(gbuf[64+t]);
            float gg = tanhf_(gbuf[128+t]);
            float og = sigmf_(gbuf[192+t]);
            c = fg*c + ig*gg;
            float h = og*tanhf_(c);
            hbuf[t] = h;
            hout[(b*128+ts)*64 + t] = h;
        }
        __syncthreads();
    }
}

// ================= policy/value heads (fp32) =================
__global__ __launch_bounds__(64) void heads_kernel(
    const float* __restrict__ hout,
    const float* __restrict__ p1w, const float* __restrict__ p1b,
    const float* __restrict__ p2w, const float* __restrict__ p2b,
    const float* __restrict__ v1w, const float* __restrict__ v1b,
    const float* __restrict__ v2w, const float* __restrict__ v2b,
    float* __restrict__ out)
{
    __shared__ alignas(16) float hbuf[64];
    __shared__ alignas(16) float a1[128];
    __shared__ alignas(16) float a2[128];
    const int lane = threadIdx.x;
    for (int fi=0; fi<4; ++fi) {
        const int f = blockIdx.x*4 + fi;
        hbuf[lane] = hout[f*64 + lane];
        __syncthreads();
        #pragma unroll
        for (int uu=0; uu<2; ++uu) {
            const int u = lane + uu*64;
            float s1 = p1b[u], s2 = v1b[u];
            const float4* wp1 = (const float4*)(p1w + u*64);
            const float4* wv1 = (const float4*)(v1w + u*64);
            #pragma unroll
            for (int k=0;k<16;k++) {
                float4 h4 = *(const float4*)(&hbuf[k*4]);
                float4 w4 = wp1[k];
                s1 += h4.x*w4.x + h4.y*w4.y + h4.z*w4.z + h4.w*w4.w;
                float4 q4 = wv1[k];
                s2 += h4.x*q4.x + h4.y*q4.y + h4.z*q4.z + h4.w*q4.w;
            }
            a1[u] = fmaxf(s1, 0.f);
            a2[u] = fmaxf(s2, 0.f);
        }
        __syncthreads();
        if (lane < 6) {
            float s = p2b[lane];
            const float* wr = p2w + lane*128;
            #pragma unroll
            for (int j=0;j<128;j++) s += a1[j]*wr[j];
            out[f*6 + lane] = s;
        }
        if (lane == 6) {
            float s = v2b[0];
            #pragma unroll
            for (int j=0;j<128;j++) s += a2[j]*v2w[j];
            out[24576 + f] = s;
        }
        __syncthreads();
    }
}

extern "C" void kernel_launch(void* const* d_in, const int* in_sizes, int n_in,
                              void* d_out, int out_size, void* d_ws, size_t ws_size,
                              hipStream_t stream) {
    const float* x       = (const float*)d_in[0];
    const float* conv0_w = (const float*)d_in[1];
    const float* conv0_b = (const float*)d_in[2];
    const float* conv_ws = (const float*)d_in[3];
    const float* conv_bs = (const float*)d_in[4];
    const float* fc_w    = (const float*)d_in[5];
    const float* fc_b    = (const float*)d_in[6];
    const float* w_ih    = (const float*)d_in[7];
    const float* w_hh    = (const float*)d_in[8];
    const float* b_ih    = (const float*)d_in[9];
    const float* b_hh    = (const float*)d_in[10];
    const float* p1_w    = (const float*)d_in[11];
    const float* p1_b    = (const float*)d_in[12];
    const float* p2_w    = (const float*)d_in[13];
    const float* p2_b    = (const float*)d_in[14];
    const float* v1_w    = (const float*)d_in[15];
    const float* v1_b    = (const float*)d_in[16];
    const float* v2_w    = (const float*)d_in[17];
    const float* v2_b    = (const float*)d_in[18];
    float* out = (float*)d_out;

    char* ws = (char*)d_ws;
    short* w0    = (short*)(ws + OFF_W0);
    short* wpk   = (short*)(ws + OFF_WP);
    short* fcp   = (short*)(ws + OFF_FCP);
    float* wihT  = (float*)(ws + OFF_WIHT);
    float* bsum  = (float*)(ws + OFF_BSUM);
    short* acts  = (short*)(ws + OFF_ACTS);
    float* xgb   = (float*)(ws + OFF_XG);
    float* hout  = (float*)(ws + OFF_HOUT);

    prep_kernel<<<1109, 256, 0, stream>>>(conv0_w, conv_ws, w_ih, b_ih, b_hh,
                                          w0, wpk, wihT, bsum);
    fc_transpose<<<64, 256, 0, stream>>>(fc_w, fcp);
    conv_stack<<<N_FRAMES/2, 256, 0, stream>>>(x, conv0_b, conv_bs, w0, wpk, acts);
    fc_xg_kernel<<<256, 256, 0, stream>>>(acts, fcp, fc_b, wihT, bsum, xgb);
    lstm_kernel<<<32, 128, 0, stream>>>(xgb, w_hh, hout);
    heads_kernel<<<1024, 64, 0, stream>>>(hout, p1_w, p1_b, p2_w, p2_b,
                                          v1_w, v1_b, v2_w, v2_b, out);
}